// Round 10
// baseline (263.206 us; speedup 1.0000x reference)
//
#include <hip/hip_runtime.h>
#include <hip/hip_bf16.h>

#define H 64
#define H3 192
#define ITEMS 16   // edges per thread in bucket hist/scatter (4096/block)

typedef __attribute__((ext_vector_type(8))) short short8;
typedef __attribute__((ext_vector_type(4))) float f32x4;

__device__ __forceinline__ float sigmoidf_(float x) {
    return 1.0f / (1.0f + __expf(-x));
}
__device__ __forceinline__ float tanhf_(float x) {
    float e = __expf(2.0f * x);
    return 1.0f - 2.0f / (e + 1.0f);
}
// f32 -> bf16 round-to-nearest-even (bit trick)
__device__ __forceinline__ unsigned short f2bf(float f) {
    unsigned u = __builtin_bit_cast(unsigned, f);
    u += 0x7FFFu + ((u >> 16) & 1u);
    return (unsigned short)(u >> 16);
}
__device__ __forceinline__ float bf2f(unsigned short s) {
    return __builtin_bit_cast(float, (unsigned)s << 16);
}

// ---------------------------------------------------------------------------
// Fused setup: [0, nbA): input linear + gates; [nbA, nbA+nbB): weight convert;
// [nbA+nbB, ...): bucket histogram. All three are independent.
__global__ __launch_bounds__(256) void setup_kernel(
    const float* __restrict__ feat, const float* __restrict__ Win,
    const float* __restrict__ bin, const float* __restrict__ Wg,
    unsigned short* __restrict__ h_bf,
    float* __restrict__ a_gate, float* __restrict__ b_gate,
    const float* __restrict__ Wih, const float* __restrict__ Whh,
    unsigned short* __restrict__ w_bf,
    const int* __restrict__ dst, int* __restrict__ bhist,
    int N, int E, int per, int nbA, int nbB, int nb_c)
{
    int bid = blockIdx.x;
    int t = threadIdx.x;
    if (bid < nbA) {
        __shared__ float sWin[16 * H];
        __shared__ float sbin[H];
        __shared__ float sWg[2 * H];
        for (int i = t; i < 16 * H; i += 256) sWin[i] = Win[i];
        if (t < H) sbin[t] = bin[t];
        if (t < 2 * H) sWg[t] = Wg[t];
        __syncthreads();

        int n = bid * 256 + t;
        if (n >= N) return;

        float f[16];
        const float4* fr = (const float4*)(feat + (size_t)n * 16);
#pragma unroll
        for (int i = 0; i < 4; i++) {
            float4 v = fr[i];
            f[4 * i + 0] = v.x; f[4 * i + 1] = v.y;
            f[4 * i + 2] = v.z; f[4 * i + 3] = v.w;
        }
        float a = 0.f, b = 0.f;
        unsigned short* brow = h_bf + (size_t)n * H;
        for (int j = 0; j < H; j++) {
            float hj = sbin[j];
#pragma unroll
            for (int k = 0; k < 16; k++) hj += f[k] * sWin[k * H + j];
            brow[j] = f2bf(hj);
            a += hj * sWg[j];
            b += hj * sWg[H + j];
        }
        a_gate[n] = a;
        b_gate[n] = b;
    } else if (bid < nbA + nbB) {
        int i = (bid - nbA) * 256 + t;
        if (i < per) w_bf[i] = f2bf(Wih[i]);
        else if (i < 2 * per) w_bf[i] = f2bf(Whh[i - per]);
    } else {
        __shared__ int lh[256];
        lh[t] = 0;
        __syncthreads();
        int base = (bid - nbA - nbB) * (256 * ITEMS);
#pragma unroll
        for (int k = 0; k < ITEMS; k++) {
            int i = base + k * 256 + t;
            if (i < E) atomicAdd(&lh[dst[i] >> 8], 1);
        }
        __syncthreads();
        bhist[t * nb_c + (bid - nbA - nbB)] = lh[t];
    }
}

// ---------------------------------------------------------------------------
// Fused exclusive scan of bhist[M] -> S (single kernel, direct-carry)
__global__ __launch_bounds__(256) void scan_fused(
    const int* __restrict__ bhist, int* __restrict__ S, int M, int E)
{
    int t = threadIdx.x;
    int b = blockIdx.x;
    int pre = b * 256;
    if (pre > M) pre = M;
    int v = 0;
    for (int k = t; k < pre; k += 256) v += bhist[k];
#pragma unroll
    for (int off = 32; off >= 1; off >>= 1) v += __shfl_xor(v, off);
    __shared__ int ws[4];
    if ((t & 63) == 0) ws[t >> 6] = v;
    __syncthreads();
    int carry = ws[0] + ws[1] + ws[2] + ws[3];

    int i = b * 256 + t;
    int x = (i < M) ? bhist[i] : 0;
    int lane = t & 63, w = t >> 6;
    int s = x;
#pragma unroll
    for (int off = 1; off < 64; off <<= 1) {
        int u = __shfl_up(s, off);
        if (lane >= off) s += u;
    }
    __shared__ int wsum[4];
    if (lane == 63) wsum[w] = s;
    __syncthreads();
    int add = 0;
    for (int k = 0; k < w; k++) add += wsum[k];
    if (i < M) S[i] = carry + s + add - x;
    else if (i == M) S[M] = E;
}

// Pass C: ranked scatter into bucket-grouped packed array.
__global__ __launch_bounds__(256) void bucket_scatter_kernel(
    const int* __restrict__ src, const int* __restrict__ dst,
    const int* __restrict__ S, unsigned* __restrict__ pk, int E, int nb_c)
{
    __shared__ int lbase[256];
    __shared__ int lrun[256];
    int t = threadIdx.x;
    lbase[t] = S[t * nb_c + blockIdx.x];
    lrun[t] = 0;
    __syncthreads();
    int base = blockIdx.x * (256 * ITEMS);
#pragma unroll
    for (int k = 0; k < ITEMS; k++) {
        int i = base + k * 256 + t;
        if (i < E) {
            int d = dst[i];
            int b = d >> 8;
            int r = atomicAdd(&lrun[b], 1);
            pk[lbase[b] + r] = ((unsigned)(d & 255) << 16) | (unsigned)src[i];
        }
    }
}

// Pass D: one block per bucket: per-dst counts -> offsets, ranked src (ushort)
__global__ __launch_bounds__(256) void bucket_finalize_kernel(
    const unsigned* __restrict__ pk, const int* __restrict__ S,
    int* __restrict__ offsets, unsigned short* __restrict__ csr16,
    int N, int E, int nb_c, int NB)
{
    __shared__ int lh[256];
    __shared__ int loff[256];
    __shared__ int lrun[256];
    int t = threadIdx.x;
    int b = blockIdx.x;
    int beg = S[b * nb_c];
    int endb = (b + 1 < NB) ? S[(b + 1) * nb_c] : E;
    lh[t] = 0; lrun[t] = 0;
    __syncthreads();
    for (int i = beg + t; i < endb; i += 256) atomicAdd(&lh[pk[i] >> 16], 1);
    __syncthreads();
    int v = lh[t];
    loff[t] = v;
    __syncthreads();
    for (int off = 1; off < 256; off <<= 1) {
        int u = (t >= off) ? loff[t - off] : 0;
        __syncthreads();
        loff[t] += u;
        __syncthreads();
    }
    int excl = loff[t] - v;
    int node = b * 256 + t;
    if (node < N) offsets[node] = beg + excl;
    if (b == NB - 1 && t == 0) offsets[N] = E;
    loff[t] = excl;
    __syncthreads();
    for (int i = beg + t; i < endb; i += 256) {
        unsigned w = pk[i];
        int d = (int)(w >> 16);
        int r = atomicAdd(&lrun[d], 1);
        csr16[beg + loff[d] + r] = (unsigned short)(w & 0xFFFFu);
    }
}

// ---------------------------------------------------------------------------
// Fused layer: aggregate (phase 1, 4 waves x 4 nodes -> LDS) + GRU MFMA
// (phase 2, wave 0, 16 nodes). Double-buffered state/gates (read *_in,
// write *_out) so blocks can proceed independently.
// C/D: col(j)=lane&15, row(node)=(lane>>4)*4+reg   [measured: m89]
__global__ __launch_bounds__(256) void layer_kernel(
    const unsigned short* __restrict__ h_in,   // [N][64] bf16 state (read)
    unsigned short* __restrict__ h_out,        // [N][64] bf16 state (write)
    const float* __restrict__ a_in, const float* __restrict__ b_in,
    float* __restrict__ a_out, float* __restrict__ b_out,
    const int* __restrict__ offsets, const unsigned short* __restrict__ csr16,
    const float* __restrict__ b_edge,
    const unsigned short* __restrict__ wih_bf, // [192][64] bf16
    const unsigned short* __restrict__ whh_bf, // [192][64] bf16
    const float* __restrict__ bih, const float* __restrict__ bhh,
    const float* __restrict__ Wg, int N)
{
    __shared__ unsigned short sx[16 * H];  // aggregated messages, 2KB

    int t = threadIdx.x;
    int wv = t >> 6;
    int lane = t & 63;
    int sub = lane >> 3;     // edge slot 0..7
    int cg  = lane & 7;      // component group (8 bf16 = 16B)
    int nbase = blockIdx.x * 16;
    float be = b_edge[0];

    // ---- phase 1: aggregate 4 nodes per wave into LDS ----
    for (int r = 0; r < 4; r++) {
        int lv = wv * 4 + r;           // local node 0..15
        int v = nbase + lv;
        if (v >= N) break;

        int beg = offsets[v];
        int end = offsets[v + 1];
        float bv = b_in[v] + be;
        float acc0[8] = {0.f, 0.f, 0.f, 0.f, 0.f, 0.f, 0.f, 0.f};
        float acc1[8] = {0.f, 0.f, 0.f, 0.f, 0.f, 0.f, 0.f, 0.f};

        for (int cs = beg; cs < end; cs += 64) {
            int m = end - cs; if (m > 64) m = 64;
            int u = 0; float w = 0.f;
            if (lane < m) {
                u = (int)csr16[cs + lane];
                w = sigmoidf_(a_in[u] + bv);
            }
            for (int j = 0; j < m; j += 16) {
                int e0 = j + sub, e1 = j + 8 + sub;
                int u0 = __shfl(u, e0 & 63);
                float w0 = __shfl(w, e0 & 63);
                int u1 = __shfl(u, e1 & 63);
                float w1 = __shfl(w, e1 & 63);
                if (e0 >= m) w0 = 0.f;
                if (e1 >= m) w1 = 0.f;
                short8 hv0 = *(const short8*)(h_in + (size_t)u0 * H + cg * 8);
                short8 hv1 = *(const short8*)(h_in + (size_t)u1 * H + cg * 8);
#pragma unroll
                for (int k = 0; k < 8; k++)
                    acc0[k] += w0 * bf2f((unsigned short)hv0[k]);
#pragma unroll
                for (int k = 0; k < 8; k++)
                    acc1[k] += w1 * bf2f((unsigned short)hv1[k]);
            }
        }
#pragma unroll
        for (int k = 0; k < 8; k++) acc0[k] += acc1[k];
#pragma unroll
        for (int mm = 8; mm < 64; mm <<= 1) {
#pragma unroll
            for (int k = 0; k < 8; k++)
                acc0[k] += __shfl_xor(acc0[k], mm);
        }
        if (sub == 0) {
            short8 o;
#pragma unroll
            for (int k = 0; k < 8; k++) o[k] = (short)f2bf(acc0[k]);
            *(short8*)(&sx[lv * H + cg * 8]) = o;
        }
    }
    __syncthreads();

    // ---- phase 2: GRU MFMA on the block's 16 nodes (wave 0 only) ----
    if (wv != 0) return;

    int c = lane & 15;      // j within tile / node-row for A
    int g = lane >> 4;      // k-group 0..3
    if (nbase >= N) return;

    int nrow = nbase + c;
    int nclamp = nrow < N ? nrow : (N - 1);

    short8 ax[2], ah[2];
#pragma unroll
    for (int ch = 0; ch < 2; ch++) {
        ax[ch] = *(const short8*)(&sx[c * H + ch * 32 + g * 8]);
        ah[ch] = *(const short8*)(h_in + (size_t)nclamp * H + ch * 32 + g * 8);
    }

    f32x4 gi[12], gh[12];
#pragma unroll
    for (int jb = 0; jb < 12; jb++) {
        gi[jb] = (f32x4){0.f, 0.f, 0.f, 0.f};
        gh[jb] = (f32x4){0.f, 0.f, 0.f, 0.f};
    }

#pragma unroll
    for (int jb = 0; jb < 12; jb++) {
        const unsigned short* wi = wih_bf + (size_t)(jb * 16 + c) * H + g * 8;
        const unsigned short* wh = whh_bf + (size_t)(jb * 16 + c) * H + g * 8;
        short8 wi0 = *(const short8*)(wi);
        short8 wi1 = *(const short8*)(wi + 32);
        short8 wh0 = *(const short8*)(wh);
        short8 wh1 = *(const short8*)(wh + 32);
        gi[jb] = __builtin_amdgcn_mfma_f32_16x16x32_bf16(ax[0], wi0, gi[jb], 0, 0, 0);
        gi[jb] = __builtin_amdgcn_mfma_f32_16x16x32_bf16(ax[1], wi1, gi[jb], 0, 0, 0);
        gh[jb] = __builtin_amdgcn_mfma_f32_16x16x32_bf16(ah[0], wh0, gh[jb], 0, 0, 0);
        gh[jb] = __builtin_amdgcn_mfma_f32_16x16x32_bf16(ah[1], wh1, gh[jb], 0, 0, 0);
    }

    float pa[4] = {0.f, 0.f, 0.f, 0.f};
    float pb[4] = {0.f, 0.f, 0.f, 0.f};
#pragma unroll
    for (int jb = 0; jb < 4; jb++) {
        int j = jb * 16 + c;
        float br = bih[j] + bhh[j];
        float bz = bih[H + j] + bhh[H + j];
        float bin_ = bih[2 * H + j];
        float bhn_ = bhh[2 * H + j];
        float wga = Wg[j], wgb = Wg[H + j];
#pragma unroll
        for (int q = 0; q < 4; q++) {
            int node = nbase + g * 4 + q;
            if (node >= N) continue;
            float r = sigmoidf_(gi[jb][q] + gh[jb][q] + br);
            float z = sigmoidf_(gi[jb + 4][q] + gh[jb + 4][q] + bz);
            float nn = tanhf_(gi[jb + 8][q] + bin_ + r * (gh[jb + 8][q] + bhn_));
            size_t idx = (size_t)node * H + j;
            float hp = bf2f(h_in[idx]);
            float ho = (1.0f - z) * nn + z * hp;
            h_out[idx] = f2bf(ho);
            pa[q] += ho * wga;
            pb[q] += ho * wgb;
        }
    }
#pragma unroll
    for (int m = 1; m < 16; m <<= 1) {
#pragma unroll
        for (int q = 0; q < 4; q++) {
            pa[q] += __shfl_xor(pa[q], m);
            pb[q] += __shfl_xor(pb[q], m);
        }
    }
    if (c == 0) {
#pragma unroll
        for (int q = 0; q < 4; q++) {
            int node = nbase + g * 4 + q;
            if (node < N) {
                a_out[node] = pa[q];
                b_out[node] = pb[q];
            }
        }
    }
}

// ---------------------------------------------------------------------------
// Final predictor: out[e] = pa[src] + pb[dst] + b_pred  (4 edges/thread)
__global__ __launch_bounds__(256) void predict_kernel(
    const int* __restrict__ src, const int* __restrict__ dst,
    const float* __restrict__ pa, const float* __restrict__ pb,
    const float* __restrict__ b_pred, float* __restrict__ out, int E)
{
    int e4 = (blockIdx.x * 256 + threadIdx.x) * 4;
    float bp = b_pred[0];
    if (e4 + 3 < E) {
        int4 s = *(const int4*)(src + e4);
        int4 d = *(const int4*)(dst + e4);
        float4 o;
        o.x = pa[s.x] + pb[d.x] + bp;
        o.y = pa[s.y] + pb[d.y] + bp;
        o.z = pa[s.z] + pb[d.z] + bp;
        o.w = pa[s.w] + pb[d.w] + bp;
        *(float4*)(out + e4) = o;
    } else {
        for (int e = e4; e < E; e++)
            out[e] = pa[src[e]] + pb[dst[e]] + bp;
    }
}

// ---------------------------------------------------------------------------
extern "C" void kernel_launch(void* const* d_in, const int* in_sizes, int n_in,
                              void* d_out, int out_size, void* d_ws, size_t ws_size,
                              hipStream_t stream) {
    const float* features = (const float*)d_in[0];
    const int*   src      = (const int*)d_in[1];
    const int*   dst      = (const int*)d_in[2];
    const float* W_in     = (const float*)d_in[3];
    const float* b_in     = (const float*)d_in[4];
    const float* W_edge   = (const float*)d_in[5];
    const float* b_edge   = (const float*)d_in[6];
    const float* Wih      = (const float*)d_in[7];
    const float* Whh      = (const float*)d_in[8];
    const float* bih      = (const float*)d_in[9];
    const float* bhh      = (const float*)d_in[10];
    const float* W_pred   = (const float*)d_in[11];
    const float* b_pred   = (const float*)d_in[12];
    float* out = (float*)d_out;

    int N = in_sizes[0] / 16;
    int E = in_sizes[1];
    int L = in_sizes[7] / (H3 * H);
    int per = L * H3 * H;

    int nb_nodes = (N + 255) / 256;
    int nb_conv  = (2 * per + 255) / 256;
    int nb_pred  = (E + 1023) / 1024;
    int nb_layer = (N + 15) / 16;

    int nb_c = (E + 256 * ITEMS - 1) / (256 * ITEMS);
    int NB   = (N + 255) / 256;
    int M    = 256 * nb_c;
    int nb_scan = (M + 1 + 255) / 256;

    // workspace layout (double-buffered state + gates)
    unsigned short* hA = (unsigned short*)d_ws;                       // N*64 bf16
    unsigned short* hB = hA + (size_t)N * H;                          // N*64 bf16
    unsigned short* w_bf = hB + (size_t)N * H;                        // 2*per bf16
    float* aA = (float*)(w_bf + 2 * per);                             // N
    float* bA = aA + N;                                               // N
    float* aB = bA + N;                                               // N
    float* bB = aB + N;                                               // N
    int* offsets  = (int*)(bB + N);                                   // N+1
    unsigned* pk  = (unsigned*)(offsets + N + 1);                     // E
    unsigned short* csr16 = (unsigned short*)(pk + E);                // E (even)
    int* bhist = (int*)(csr16 + E);                                   // M
    int* sbh   = bhist + M;                                           // M+1

    // fused setup: input linear | weight convert | bucket hist
    setup_kernel<<<nb_nodes + nb_conv + nb_c, 256, 0, stream>>>(
        features, W_in, b_in, W_edge, hA, aA, bA,
        Wih, Whh, w_bf, dst, bhist,
        N, E, per, nb_nodes, nb_conv, nb_c);

    // CSR build (bucket sort)
    scan_fused<<<nb_scan, 256, 0, stream>>>(bhist, sbh, M, E);
    bucket_scatter_kernel<<<nb_c, 256, 0, stream>>>(src, dst, sbh, pk, E, nb_c);
    bucket_finalize_kernel<<<NB, 256, 0, stream>>>(pk, sbh, offsets, csr16, N, E, nb_c, NB);

    // fused per-layer aggregate+GRU with ping-pong buffers
    unsigned short* h_in = hA;  unsigned short* h_out = hB;
    float *a_in = aA, *b_in2 = bA, *a_out = aB, *b_out = bB;
    for (int l = 0; l < L; l++) {
        const float* Wg = (l < L - 1) ? W_edge : W_pred;
        layer_kernel<<<nb_layer, 256, 0, stream>>>(
            h_in, h_out, a_in, b_in2, a_out, b_out,
            offsets, csr16, b_edge,
            w_bf + (size_t)l * H3 * H,
            w_bf + (size_t)per + (size_t)l * H3 * H,
            bih + (size_t)l * H3, bhh + (size_t)l * H3,
            Wg, N);
        // swap
        unsigned short* th = h_in; h_in = h_out; h_out = th;
        float* tf;
        tf = a_in; a_in = a_out; a_out = tf;
        tf = b_in2; b_in2 = b_out; b_out = tf;
    }

    predict_kernel<<<nb_pred, 256, 0, stream>>>(src, dst, a_in, b_in2, b_pred, out, E);
}

// Round 11
// 229.328 us; speedup vs baseline: 1.1477x; 1.1477x over previous
//
#include <hip/hip_runtime.h>
#include <hip/hip_bf16.h>

#define H 64
#define H3 192
#define ITEMS 16   // edges per thread in bucket hist/scatter (4096/block)

typedef __attribute__((ext_vector_type(8))) short short8;
typedef __attribute__((ext_vector_type(4))) float f32x4;

__device__ __forceinline__ float sigmoidf_(float x) {
    return 1.0f / (1.0f + __expf(-x));
}
__device__ __forceinline__ float tanhf_(float x) {
    float e = __expf(2.0f * x);
    return 1.0f - 2.0f / (e + 1.0f);
}
// f32 -> bf16 round-to-nearest-even (bit trick)
__device__ __forceinline__ unsigned short f2bf(float f) {
    unsigned u = __builtin_bit_cast(unsigned, f);
    u += 0x7FFFu + ((u >> 16) & 1u);
    return (unsigned short)(u >> 16);
}
__device__ __forceinline__ float bf2f(unsigned short s) {
    return __builtin_bit_cast(float, (unsigned)s << 16);
}

// ---------------------------------------------------------------------------
// Fused setup: [0, nbA): input linear + gates; [nbA, nbA+nbB): weight convert;
// [nbA+nbB, ...): bucket histogram. All three are independent.
__global__ __launch_bounds__(256) void setup_kernel(
    const float* __restrict__ feat, const float* __restrict__ Win,
    const float* __restrict__ bin, const float* __restrict__ Wg,
    unsigned short* __restrict__ h_bf,
    float* __restrict__ a_gate, float* __restrict__ b_gate,
    const float* __restrict__ Wih, const float* __restrict__ Whh,
    unsigned short* __restrict__ w_bf,
    const int* __restrict__ dst, int* __restrict__ bhist,
    int N, int E, int per, int nbA, int nbB, int nb_c)
{
    int bid = blockIdx.x;
    int t = threadIdx.x;
    if (bid < nbA) {
        // ---- input linear + layer-0 gates ----
        __shared__ float sWin[16 * H];
        __shared__ float sbin[H];
        __shared__ float sWg[2 * H];
        for (int i = t; i < 16 * H; i += 256) sWin[i] = Win[i];
        if (t < H) sbin[t] = bin[t];
        if (t < 2 * H) sWg[t] = Wg[t];
        __syncthreads();

        int n = bid * 256 + t;
        if (n >= N) return;

        float f[16];
        const float4* fr = (const float4*)(feat + (size_t)n * 16);
#pragma unroll
        for (int i = 0; i < 4; i++) {
            float4 v = fr[i];
            f[4 * i + 0] = v.x; f[4 * i + 1] = v.y;
            f[4 * i + 2] = v.z; f[4 * i + 3] = v.w;
        }
        float a = 0.f, b = 0.f;
        unsigned short* brow = h_bf + (size_t)n * H;
        for (int jb = 0; jb < 8; jb++) {
            short8 o;
#pragma unroll
            for (int jj = 0; jj < 8; jj++) {
                int j = jb * 8 + jj;
                float hj = sbin[j];
#pragma unroll
                for (int k = 0; k < 16; k++) hj += f[k] * sWin[k * H + j];
                o[jj] = (short)f2bf(hj);
                a += hj * sWg[j];
                b += hj * sWg[H + j];
            }
            *(short8*)(brow + jb * 8) = o;
        }
        a_gate[n] = a;
        b_gate[n] = b;
    } else if (bid < nbA + nbB) {
        // ---- weights f32 -> bf16 ----
        int i = (bid - nbA) * 256 + t;
        if (i < per) w_bf[i] = f2bf(Wih[i]);
        else if (i < 2 * per) w_bf[i] = f2bf(Whh[i - per]);
    } else {
        // ---- bucket histogram (bucket = dst>>8) ----
        __shared__ int lh[256];
        lh[t] = 0;
        __syncthreads();
        int base = (bid - nbA - nbB) * (256 * ITEMS);
#pragma unroll
        for (int k = 0; k < ITEMS; k++) {
            int i = base + k * 256 + t;
            if (i < E) atomicAdd(&lh[dst[i] >> 8], 1);
        }
        __syncthreads();
        bhist[t * nb_c + (bid - nbA - nbB)] = lh[t];
    }
}

// ---------------------------------------------------------------------------
// multi-block exclusive scan pass 1 (block-local prefix + block totals)
__global__ __launch_bounds__(256) void scan_pass1(
    const int* __restrict__ deg, int* __restrict__ locals,
    int* __restrict__ bsum, int N)
{
    int t = threadIdx.x;
    int i = blockIdx.x * 256 + t;
    int v = (i < N) ? deg[i] : 0;
    int lane = t & 63, w = t >> 6;
    int s = v;
#pragma unroll
    for (int off = 1; off < 64; off <<= 1) {
        int u = __shfl_up(s, off);
        if (lane >= off) s += u;
    }
    __shared__ int wsum[4];
    if (lane == 63) wsum[w] = s;
    __syncthreads();
    int add = 0;
    for (int k = 0; k < w; k++) add += wsum[k];
    if (i < N) locals[i] = s + add - v;
    if (t == 255) bsum[blockIdx.x] = s + add;
}

// pass 3 with per-block carry recompute over the small bsum array:
// carry(b) = sum of bsum[0..b), computed by a block-wide reduction.
__global__ __launch_bounds__(256) void scan_pass3c(
    const int* __restrict__ locals, const int* __restrict__ bsum,
    int* __restrict__ S, int M, int E, int mb)
{
    int t = threadIdx.x;
    int b = blockIdx.x;
    int v = 0;
    for (int k = t; k < b && k < mb; k += 256) v += bsum[k];
#pragma unroll
    for (int off = 32; off >= 1; off >>= 1) v += __shfl_xor(v, off);
    __shared__ int ws[4];
    if ((t & 63) == 0) ws[t >> 6] = v;
    __syncthreads();
    int carry = ws[0] + ws[1] + ws[2] + ws[3];

    int i = b * 256 + t;
    if (i < M) S[i] = locals[i] + carry;
    else if (i == M) S[M] = E;
}

// Pass C: ranked scatter into bucket-grouped packed array.
__global__ __launch_bounds__(256) void bucket_scatter_kernel(
    const int* __restrict__ src, const int* __restrict__ dst,
    const int* __restrict__ S, unsigned* __restrict__ pk, int E, int nb_c)
{
    __shared__ int lbase[256];
    __shared__ int lrun[256];
    int t = threadIdx.x;
    lbase[t] = S[t * nb_c + blockIdx.x];
    lrun[t] = 0;
    __syncthreads();
    int base = blockIdx.x * (256 * ITEMS);
#pragma unroll
    for (int k = 0; k < ITEMS; k++) {
        int i = base + k * 256 + t;
        if (i < E) {
            int d = dst[i];
            int b = d >> 8;
            int r = atomicAdd(&lrun[b], 1);
            pk[lbase[b] + r] = ((unsigned)(d & 255) << 16) | (unsigned)src[i];
        }
    }
}

// Pass D: one block per bucket: per-dst counts -> offsets, ranked src (ushort)
__global__ __launch_bounds__(256) void bucket_finalize_kernel(
    const unsigned* __restrict__ pk, const int* __restrict__ S,
    int* __restrict__ offsets, unsigned short* __restrict__ csr16,
    int N, int E, int nb_c, int NB)
{
    __shared__ int lh[256];
    __shared__ int loff[256];
    __shared__ int lrun[256];
    int t = threadIdx.x;
    int b = blockIdx.x;
    int beg = S[b * nb_c];
    int endb = (b + 1 < NB) ? S[(b + 1) * nb_c] : E;
    lh[t] = 0; lrun[t] = 0;
    __syncthreads();
    for (int i = beg + t; i < endb; i += 256) atomicAdd(&lh[pk[i] >> 16], 1);
    __syncthreads();
    int v = lh[t];
    loff[t] = v;
    __syncthreads();
    for (int off = 1; off < 256; off <<= 1) {
        int u = (t >= off) ? loff[t - off] : 0;
        __syncthreads();
        loff[t] += u;
        __syncthreads();
    }
    int excl = loff[t] - v;
    int node = b * 256 + t;
    if (node < N) offsets[node] = beg + excl;
    if (b == NB - 1 && t == 0) offsets[N] = E;
    loff[t] = excl;
    __syncthreads();
    for (int i = beg + t; i < endb; i += 256) {
        unsigned w = pk[i];
        int d = (int)(w >> 16);
        int r = atomicAdd(&lrun[d], 1);
        csr16[beg + loff[d] + r] = (unsigned short)(w & 0xFFFFu);
    }
}

// ---------------------------------------------------------------------------
// Aggregate: h_new[v] = sum_{e: dst==v} sigmoid(a[src]+b[v]+be) * h[src]
// wave-per-node; 8x8 lane groups, 2x unrolled -> 16 rows in flight per iter.
__global__ __launch_bounds__(256) void aggregate_kernel(
    const unsigned short* __restrict__ h_bf, const float* __restrict__ a_gate,
    const float* __restrict__ b_gate, const int* __restrict__ offsets,
    const unsigned short* __restrict__ csr16, const float* __restrict__ b_edge,
    unsigned short* __restrict__ hnew_bf, int N)
{
    int wid = threadIdx.x >> 6;
    int lane = threadIdx.x & 63;
    int sub = lane >> 3;     // edge slot 0..7
    int cg  = lane & 7;      // component group (8 bf16 = 16B)
    int v = blockIdx.x * 4 + wid;
    if (v >= N) return;

    int beg = offsets[v];
    int end = offsets[v + 1];
    float bv = b_gate[v] + b_edge[0];
    float acc0[8] = {0.f, 0.f, 0.f, 0.f, 0.f, 0.f, 0.f, 0.f};
    float acc1[8] = {0.f, 0.f, 0.f, 0.f, 0.f, 0.f, 0.f, 0.f};

    for (int cs = beg; cs < end; cs += 64) {
        int m = end - cs; if (m > 64) m = 64;
        int u = 0; float w = 0.f;
        if (lane < m) {
            u = (int)csr16[cs + lane];
            w = sigmoidf_(a_gate[u] + bv);
        }
        for (int j = 0; j < m; j += 16) {
            int e0 = j + sub, e1 = j + 8 + sub;
            int u0 = __shfl(u, e0 & 63);
            float w0 = __shfl(w, e0 & 63);
            int u1 = __shfl(u, e1 & 63);
            float w1 = __shfl(w, e1 & 63);
            if (e0 >= m) w0 = 0.f;
            if (e1 >= m) w1 = 0.f;
            short8 hv0 = *(const short8*)(h_bf + (size_t)u0 * H + cg * 8);
            short8 hv1 = *(const short8*)(h_bf + (size_t)u1 * H + cg * 8);
#pragma unroll
            for (int k = 0; k < 8; k++)
                acc0[k] += w0 * bf2f((unsigned short)hv0[k]);
#pragma unroll
            for (int k = 0; k < 8; k++)
                acc1[k] += w1 * bf2f((unsigned short)hv1[k]);
        }
    }
#pragma unroll
    for (int k = 0; k < 8; k++) acc0[k] += acc1[k];
    // reduce across the 8 sub-groups (lane bits 3,4,5)
#pragma unroll
    for (int mm = 8; mm < 64; mm <<= 1) {
#pragma unroll
        for (int k = 0; k < 8; k++)
            acc0[k] += __shfl_xor(acc0[k], mm);
    }
    if (sub == 0) {
        short8 o;
#pragma unroll
        for (int k = 0; k < 8; k++) o[k] = (short)f2bf(acc0[k]);
        *(short8*)(hnew_bf + (size_t)v * H + cg * 8) = o;
    }
}

// ---------------------------------------------------------------------------
// Fused GRU via MFMA bf16. Wave computes 16 nodes. State lives in bf16 only.
// C/D: col(j)=lane&15, row(node)=(lane>>4)*4+reg   [measured: m89]
__global__ __launch_bounds__(256) void gru_mfma_kernel(
    const unsigned short* __restrict__ x_bf,   // [N][64] bf16 (h_new)
    unsigned short* __restrict__ h_bf,         // [N][64] bf16 state, in-place
    const unsigned short* __restrict__ wih_bf, // [192][64] bf16
    const unsigned short* __restrict__ whh_bf, // [192][64] bf16
    const float* __restrict__ bih, const float* __restrict__ bhh,
    const float* __restrict__ Wg,
    float* __restrict__ a_gate, float* __restrict__ b_gate, int N)
{
    int lane = threadIdx.x & 63;
    int wv = threadIdx.x >> 6;
    int c = lane & 15;      // j within tile / node-row for A
    int g = lane >> 4;      // k-group 0..3
    int nbase = blockIdx.x * 64 + wv * 16;
    if (nbase >= N) return;

    int nrow = nbase + c;
    int nclamp = nrow < N ? nrow : (N - 1);

    short8 ax[2], ah[2];
#pragma unroll
    for (int ch = 0; ch < 2; ch++) {
        ax[ch] = *(const short8*)(x_bf + (size_t)nclamp * H + ch * 32 + g * 8);
        ah[ch] = *(const short8*)(h_bf + (size_t)nclamp * H + ch * 32 + g * 8);
    }

    f32x4 gi[12], gh[12];
#pragma unroll
    for (int jb = 0; jb < 12; jb++) {
        gi[jb] = (f32x4){0.f, 0.f, 0.f, 0.f};
        gh[jb] = (f32x4){0.f, 0.f, 0.f, 0.f};
    }

#pragma unroll
    for (int jb = 0; jb < 12; jb++) {
        const unsigned short* wi = wih_bf + (size_t)(jb * 16 + c) * H + g * 8;
        const unsigned short* wh = whh_bf + (size_t)(jb * 16 + c) * H + g * 8;
        short8 wi0 = *(const short8*)(wi);
        short8 wi1 = *(const short8*)(wi + 32);
        short8 wh0 = *(const short8*)(wh);
        short8 wh1 = *(const short8*)(wh + 32);
        gi[jb] = __builtin_amdgcn_mfma_f32_16x16x32_bf16(ax[0], wi0, gi[jb], 0, 0, 0);
        gi[jb] = __builtin_amdgcn_mfma_f32_16x16x32_bf16(ax[1], wi1, gi[jb], 0, 0, 0);
        gh[jb] = __builtin_amdgcn_mfma_f32_16x16x32_bf16(ah[0], wh0, gh[jb], 0, 0, 0);
        gh[jb] = __builtin_amdgcn_mfma_f32_16x16x32_bf16(ah[1], wh1, gh[jb], 0, 0, 0);
    }

    float pa[4] = {0.f, 0.f, 0.f, 0.f};
    float pb[4] = {0.f, 0.f, 0.f, 0.f};
#pragma unroll
    for (int jb = 0; jb < 4; jb++) {
        int j = jb * 16 + c;
        float br = bih[j] + bhh[j];
        float bz = bih[H + j] + bhh[H + j];
        float bin_ = bih[2 * H + j];
        float bhn_ = bhh[2 * H + j];
        float wga = Wg[j], wgb = Wg[H + j];
#pragma unroll
        for (int q = 0; q < 4; q++) {
            int node = nbase + g * 4 + q;
            float r = sigmoidf_(gi[jb][q] + gh[jb][q] + br);
            float z = sigmoidf_(gi[jb + 4][q] + gh[jb + 4][q] + bz);
            float nn = tanhf_(gi[jb + 8][q] + bin_ + r * (gh[jb + 8][q] + bhn_));
            size_t idx = (size_t)node * H + j;
            float hp = bf2f(h_bf[idx]);
            float ho = (1.0f - z) * nn + z * hp;
            h_bf[idx] = f2bf(ho);
            pa[q] += ho * wga;
            pb[q] += ho * wgb;
        }
    }
#pragma unroll
    for (int m = 1; m < 16; m <<= 1) {
#pragma unroll
        for (int q = 0; q < 4; q++) {
            pa[q] += __shfl_xor(pa[q], m);
            pb[q] += __shfl_xor(pb[q], m);
        }
    }
    if (c == 0) {
#pragma unroll
        for (int q = 0; q < 4; q++) {
            int node = nbase + g * 4 + q;
            a_gate[node] = pa[q];
            b_gate[node] = pb[q];
        }
    }
}

// ---------------------------------------------------------------------------
// Final predictor: out[e] = pa[src] + pb[dst] + b_pred  (4 edges/thread)
__global__ __launch_bounds__(256) void predict_kernel(
    const int* __restrict__ src, const int* __restrict__ dst,
    const float* __restrict__ pa, const float* __restrict__ pb,
    const float* __restrict__ b_pred, float* __restrict__ out, int E)
{
    int e4 = (blockIdx.x * 256 + threadIdx.x) * 4;
    float bp = b_pred[0];
    if (e4 + 3 < E) {
        int4 s = *(const int4*)(src + e4);
        int4 d = *(const int4*)(dst + e4);
        float4 o;
        o.x = pa[s.x] + pb[d.x] + bp;
        o.y = pa[s.y] + pb[d.y] + bp;
        o.z = pa[s.z] + pb[d.z] + bp;
        o.w = pa[s.w] + pb[d.w] + bp;
        *(float4*)(out + e4) = o;
    } else {
        for (int e = e4; e < E; e++)
            out[e] = pa[src[e]] + pb[dst[e]] + bp;
    }
}

// ---------------------------------------------------------------------------
extern "C" void kernel_launch(void* const* d_in, const int* in_sizes, int n_in,
                              void* d_out, int out_size, void* d_ws, size_t ws_size,
                              hipStream_t stream) {
    const float* features = (const float*)d_in[0];
    const int*   src      = (const int*)d_in[1];
    const int*   dst      = (const int*)d_in[2];
    const float* W_in     = (const float*)d_in[3];
    const float* b_in     = (const float*)d_in[4];
    const float* W_edge   = (const float*)d_in[5];
    const float* b_edge   = (const float*)d_in[6];
    const float* Wih      = (const float*)d_in[7];
    const float* Whh      = (const float*)d_in[8];
    const float* bih      = (const float*)d_in[9];
    const float* bhh      = (const float*)d_in[10];
    const float* W_pred   = (const float*)d_in[11];
    const float* b_pred   = (const float*)d_in[12];
    float* out = (float*)d_out;

    int N = in_sizes[0] / 16;
    int E = in_sizes[1];
    int L = in_sizes[7] / (H3 * H);
    int per = L * H3 * H;

    int nb_nodes = (N + 255) / 256;
    int nb_agg   = (N + 3) / 4;
    int nb_gru   = (N + 63) / 64;
    int nb_conv  = (2 * per + 255) / 256;
    int nb_pred  = (E + 1023) / 1024;

    int nb_c = (E + 256 * ITEMS - 1) / (256 * ITEMS);
    int NB   = (N + 255) / 256;
    int M    = 256 * nb_c;
    int mb   = (M + 255) / 256;
    int nb_s3 = (M + 1 + 255) / 256;

    // workspace layout
    unsigned short* h_bf = (unsigned short*)d_ws;                     // N*64 bf16
    unsigned short* hnew_bf = h_bf + (size_t)N * H;                   // N*64 bf16
    unsigned short* w_bf = hnew_bf + (size_t)N * H;                   // 2*per bf16
    float* a_gate = (float*)(w_bf + 2 * per);                         // N
    float* b_gate = a_gate + N;                                       // N
    int* offsets  = (int*)(b_gate + N);                               // N+1
    unsigned* pk  = (unsigned*)(offsets + N + 1);                     // E
    unsigned short* csr16 = (unsigned short*)(pk + E);                // E (even)
    int* bhist = (int*)(csr16 + E);                                   // M
    int* bloc  = bhist + M;                                           // M
    int* sbh   = bloc + M;                                            // M+1
    int* bsum  = sbh + M + 1;                                         // mb

    // fused setup: input linear | weight convert | bucket hist
    setup_kernel<<<nb_nodes + nb_conv + nb_c, 256, 0, stream>>>(
        features, W_in, b_in, W_edge, h_bf, a_gate, b_gate,
        Wih, Whh, w_bf, dst, bhist,
        N, E, per, nb_nodes, nb_conv, nb_c);

    // CSR build (bucket sort)
    scan_pass1<<<mb, 256, 0, stream>>>(bhist, bloc, bsum, M);
    scan_pass3c<<<nb_s3, 256, 0, stream>>>(bloc, bsum, sbh, M, E, mb);
    bucket_scatter_kernel<<<nb_c, 256, 0, stream>>>(src, dst, sbh, pk, E, nb_c);
    bucket_finalize_kernel<<<NB, 256, 0, stream>>>(pk, sbh, offsets, csr16, N, E, nb_c, NB);

    for (int l = 0; l < L; l++) {
        aggregate_kernel<<<nb_agg, 256, 0, stream>>>(
            h_bf, a_gate, b_gate, offsets, csr16, b_edge, hnew_bf, N);
        const float* Wg = (l < L - 1) ? W_edge : W_pred;
        gru_mfma_kernel<<<nb_gru, 256, 0, stream>>>(
            hnew_bf, h_bf,
            w_bf + (size_t)l * H3 * H,
            w_bf + (size_t)per + (size_t)l * H3 * H,
            bih + (size_t)l * H3, bhh + (size_t)l * H3,
            Wg, a_gate, b_gate, N);
    }

    predict_kernel<<<nb_pred, 256, 0, stream>>>(src, dst, a_gate, b_gate, b_pred, out, E);
}

// Round 12
// 220.149 us; speedup vs baseline: 1.1956x; 1.0417x over previous
//
#include <hip/hip_runtime.h>
#include <hip/hip_bf16.h>

#define H 64
#define H3 192
#define ITEMS 16   // edges per thread in bucket hist (4096/block of 256)

typedef __attribute__((ext_vector_type(8))) short short8;
typedef __attribute__((ext_vector_type(4))) float f32x4;

__device__ __forceinline__ float sigmoidf_(float x) {
    return 1.0f / (1.0f + __expf(-x));
}
__device__ __forceinline__ float tanhf_(float x) {
    float e = __expf(2.0f * x);
    return 1.0f - 2.0f / (e + 1.0f);
}
// f32 -> bf16 round-to-nearest-even (bit trick)
__device__ __forceinline__ unsigned short f2bf(float f) {
    unsigned u = __builtin_bit_cast(unsigned, f);
    u += 0x7FFFu + ((u >> 16) & 1u);
    return (unsigned short)(u >> 16);
}
__device__ __forceinline__ float bf2f(unsigned short s) {
    return __builtin_bit_cast(float, (unsigned)s << 16);
}

// ---------------------------------------------------------------------------
// Fused setup: [0, nbA): input linear + gates; [nbA, nbA+nbB): weight convert;
// [nbA+nbB, ...): bucket histogram. All three are independent.
__global__ __launch_bounds__(256) void setup_kernel(
    const float* __restrict__ feat, const float* __restrict__ Win,
    const float* __restrict__ bin, const float* __restrict__ Wg,
    unsigned short* __restrict__ h_bf,
    float* __restrict__ a_gate, float* __restrict__ b_gate,
    const float* __restrict__ Wih, const float* __restrict__ Whh,
    unsigned short* __restrict__ w_bf,
    const int* __restrict__ dst, int* __restrict__ bhist,
    int N, int E, int per, int nbA, int nbB, int nb_c)
{
    int bid = blockIdx.x;
    int t = threadIdx.x;
    if (bid < nbA) {
        // ---- input linear + layer-0 gates ----
        __shared__ float sWin[16 * H];
        __shared__ float sbin[H];
        __shared__ float sWg[2 * H];
        for (int i = t; i < 16 * H; i += 256) sWin[i] = Win[i];
        if (t < H) sbin[t] = bin[t];
        if (t < 2 * H) sWg[t] = Wg[t];
        __syncthreads();

        int n = bid * 256 + t;
        if (n >= N) return;

        float f[16];
        const float4* fr = (const float4*)(feat + (size_t)n * 16);
#pragma unroll
        for (int i = 0; i < 4; i++) {
            float4 v = fr[i];
            f[4 * i + 0] = v.x; f[4 * i + 1] = v.y;
            f[4 * i + 2] = v.z; f[4 * i + 3] = v.w;
        }
        float a = 0.f, b = 0.f;
        unsigned short* brow = h_bf + (size_t)n * H;
        for (int jb = 0; jb < 8; jb++) {
            short8 o;
#pragma unroll
            for (int jj = 0; jj < 8; jj++) {
                int j = jb * 8 + jj;
                float hj = sbin[j];
#pragma unroll
                for (int k = 0; k < 16; k++) hj += f[k] * sWin[k * H + j];
                o[jj] = (short)f2bf(hj);
                a += hj * sWg[j];
                b += hj * sWg[H + j];
            }
            *(short8*)(brow + jb * 8) = o;
        }
        a_gate[n] = a;
        b_gate[n] = b;
    } else if (bid < nbA + nbB) {
        // ---- weights f32 -> bf16 ----
        int i = (bid - nbA) * 256 + t;
        if (i < per) w_bf[i] = f2bf(Wih[i]);
        else if (i < 2 * per) w_bf[i] = f2bf(Whh[i - per]);
    } else {
        // ---- bucket histogram (bucket = dst>>8) ----
        __shared__ int lh[256];
        lh[t] = 0;
        __syncthreads();
        int base = (bid - nbA - nbB) * (256 * ITEMS);
#pragma unroll
        for (int k = 0; k < ITEMS; k++) {
            int i = base + k * 256 + t;
            if (i < E) atomicAdd(&lh[dst[i] >> 8], 1);
        }
        __syncthreads();
        bhist[t * nb_c + (bid - nbA - nbB)] = lh[t];
    }
}

// ---------------------------------------------------------------------------
// multi-block exclusive scan pass 1 (block-local prefix + block totals)
__global__ __launch_bounds__(256) void scan_pass1(
    const int* __restrict__ deg, int* __restrict__ locals,
    int* __restrict__ bsum, int N)
{
    int t = threadIdx.x;
    int i = blockIdx.x * 256 + t;
    int v = (i < N) ? deg[i] : 0;
    int lane = t & 63, w = t >> 6;
    int s = v;
#pragma unroll
    for (int off = 1; off < 64; off <<= 1) {
        int u = __shfl_up(s, off);
        if (lane >= off) s += u;
    }
    __shared__ int wsum[4];
    if (lane == 63) wsum[w] = s;
    __syncthreads();
    int add = 0;
    for (int k = 0; k < w; k++) add += wsum[k];
    if (i < N) locals[i] = s + add - v;
    if (t == 255) bsum[blockIdx.x] = s + add;
}

// pass 3 with per-block carry recompute over the small bsum array
__global__ __launch_bounds__(256) void scan_pass3c(
    const int* __restrict__ locals, const int* __restrict__ bsum,
    int* __restrict__ S, int M, int E, int mb)
{
    int t = threadIdx.x;
    int b = blockIdx.x;
    int v = 0;
    for (int k = t; k < b && k < mb; k += 256) v += bsum[k];
#pragma unroll
    for (int off = 32; off >= 1; off >>= 1) v += __shfl_xor(v, off);
    __shared__ int ws[4];
    if ((t & 63) == 0) ws[t >> 6] = v;
    __syncthreads();
    int carry = ws[0] + ws[1] + ws[2] + ws[3];

    int i = b * 256 + t;
    if (i < M) S[i] = locals[i] + carry;
    else if (i == M) S[M] = E;
}

// Pass C: ranked scatter into bucket-grouped packed array.
// 1024 threads x 4 edges (int4) = 4096 edges/block; 16 waves/block for TLP.
__global__ __launch_bounds__(1024) void bucket_scatter_kernel(
    const int* __restrict__ src, const int* __restrict__ dst,
    const int* __restrict__ S, unsigned* __restrict__ pk, int E, int nb_c)
{
    __shared__ int lbase[256];
    __shared__ int lrun[256];
    int t = threadIdx.x;
    if (t < 256) {
        lbase[t] = S[t * nb_c + blockIdx.x];
        lrun[t] = 0;
    }
    __syncthreads();
    int i4 = blockIdx.x * 4096 + t * 4;
    if (i4 + 3 < E) {
        int4 s = *(const int4*)(src + i4);
        int4 d = *(const int4*)(dst + i4);
        int ss[4] = {s.x, s.y, s.z, s.w};
        int dd[4] = {d.x, d.y, d.z, d.w};
#pragma unroll
        for (int k = 0; k < 4; k++) {
            int b = dd[k] >> 8;
            int r = atomicAdd(&lrun[b], 1);
            pk[lbase[b] + r] = ((unsigned)(dd[k] & 255) << 16) | (unsigned)ss[k];
        }
    } else {
        for (int i = i4; i < E; i++) {
            int d = dst[i];
            int b = d >> 8;
            int r = atomicAdd(&lrun[b], 1);
            pk[lbase[b] + r] = ((unsigned)(d & 255) << 16) | (unsigned)src[i];
        }
    }
}

// Pass D: one 1024-thread block per bucket: per-dst counts -> offsets,
// ranked src (ushort) into the bucket's contiguous csr region.
__global__ __launch_bounds__(1024) void bucket_finalize_kernel(
    const unsigned* __restrict__ pk, const int* __restrict__ S,
    int* __restrict__ offsets, unsigned short* __restrict__ csr16,
    int N, int E, int nb_c, int NB)
{
    __shared__ int lh[256];
    __shared__ int loff[256];
    __shared__ int lrun[256];
    int t = threadIdx.x;
    int b = blockIdx.x;
    int beg = S[b * nb_c];
    int endb = (b + 1 < NB) ? S[(b + 1) * nb_c] : E;
    if (t < 256) { lh[t] = 0; lrun[t] = 0; }
    __syncthreads();
    for (int i = beg + t; i < endb; i += 1024) atomicAdd(&lh[pk[i] >> 16], 1);
    __syncthreads();
    int v = (t < 256) ? lh[t] : 0;
    if (t < 256) loff[t] = v;
    __syncthreads();
    for (int off = 1; off < 256; off <<= 1) {
        int u = (t >= off && t < 256) ? loff[t - off] : 0;
        __syncthreads();
        if (t < 256) loff[t] += u;
        __syncthreads();
    }
    if (t < 256) {
        int excl = loff[t] - v;
        int node = b * 256 + t;
        if (node < N) offsets[node] = beg + excl;
        loff[t] = excl;
    }
    if (b == NB - 1 && t == 0) offsets[N] = E;
    __syncthreads();
    for (int i = beg + t; i < endb; i += 1024) {
        unsigned w = pk[i];
        int d = (int)(w >> 16);
        int r = atomicAdd(&lrun[d], 1);
        csr16[beg + loff[d] + r] = (unsigned short)(w & 0xFFFFu);
    }
}

// ---------------------------------------------------------------------------
// Aggregate: h_new[v] = sum_{e: dst==v} sigmoid(a[src]+b[v]+be) * h[src]
// wave-per-node; 8x8 lane groups, 2x unrolled -> 16 rows in flight per iter.
__global__ __launch_bounds__(256) void aggregate_kernel(
    const unsigned short* __restrict__ h_bf, const float* __restrict__ a_gate,
    const float* __restrict__ b_gate, const int* __restrict__ offsets,
    const unsigned short* __restrict__ csr16, const float* __restrict__ b_edge,
    unsigned short* __restrict__ hnew_bf, int N)
{
    int wid = threadIdx.x >> 6;
    int lane = threadIdx.x & 63;
    int sub = lane >> 3;     // edge slot 0..7
    int cg  = lane & 7;      // component group (8 bf16 = 16B)
    int v = blockIdx.x * 4 + wid;
    if (v >= N) return;

    int beg = offsets[v];
    int end = offsets[v + 1];
    float bv = b_gate[v] + b_edge[0];
    float acc0[8] = {0.f, 0.f, 0.f, 0.f, 0.f, 0.f, 0.f, 0.f};
    float acc1[8] = {0.f, 0.f, 0.f, 0.f, 0.f, 0.f, 0.f, 0.f};

    for (int cs = beg; cs < end; cs += 64) {
        int m = end - cs; if (m > 64) m = 64;
        int u = 0; float w = 0.f;
        if (lane < m) {
            u = (int)csr16[cs + lane];
            w = sigmoidf_(a_gate[u] + bv);
        }
        for (int j = 0; j < m; j += 16) {
            int e0 = j + sub, e1 = j + 8 + sub;
            int u0 = __shfl(u, e0 & 63);
            float w0 = __shfl(w, e0 & 63);
            int u1 = __shfl(u, e1 & 63);
            float w1 = __shfl(w, e1 & 63);
            if (e0 >= m) w0 = 0.f;
            if (e1 >= m) w1 = 0.f;
            short8 hv0 = *(const short8*)(h_bf + (size_t)u0 * H + cg * 8);
            short8 hv1 = *(const short8*)(h_bf + (size_t)u1 * H + cg * 8);
#pragma unroll
            for (int k = 0; k < 8; k++)
                acc0[k] += w0 * bf2f((unsigned short)hv0[k]);
#pragma unroll
            for (int k = 0; k < 8; k++)
                acc1[k] += w1 * bf2f((unsigned short)hv1[k]);
        }
    }
#pragma unroll
    for (int k = 0; k < 8; k++) acc0[k] += acc1[k];
    // reduce across the 8 sub-groups (lane bits 3,4,5)
#pragma unroll
    for (int mm = 8; mm < 64; mm <<= 1) {
#pragma unroll
        for (int k = 0; k < 8; k++)
            acc0[k] += __shfl_xor(acc0[k], mm);
    }
    if (sub == 0) {
        short8 o;
#pragma unroll
        for (int k = 0; k < 8; k++) o[k] = (short)f2bf(acc0[k]);
        *(short8*)(hnew_bf + (size_t)v * H + cg * 8) = o;
    }
}

// ---------------------------------------------------------------------------
// Fused GRU via MFMA bf16. Wave computes 16 nodes. State lives in bf16 only.
// C/D: col(j)=lane&15, row(node)=(lane>>4)*4+reg   [measured: m89]
__global__ __launch_bounds__(256) void gru_mfma_kernel(
    const unsigned short* __restrict__ x_bf,   // [N][64] bf16 (h_new)
    unsigned short* __restrict__ h_bf,         // [N][64] bf16 state, in-place
    const unsigned short* __restrict__ wih_bf, // [192][64] bf16
    const unsigned short* __restrict__ whh_bf, // [192][64] bf16
    const float* __restrict__ bih, const float* __restrict__ bhh,
    const float* __restrict__ Wg,
    float* __restrict__ a_gate, float* __restrict__ b_gate, int N)
{
    int lane = threadIdx.x & 63;
    int wv = threadIdx.x >> 6;
    int c = lane & 15;      // j within tile / node-row for A
    int g = lane >> 4;      // k-group 0..3
    int nbase = blockIdx.x * 64 + wv * 16;
    if (nbase >= N) return;

    int nrow = nbase + c;
    int nclamp = nrow < N ? nrow : (N - 1);

    short8 ax[2], ah[2];
#pragma unroll
    for (int ch = 0; ch < 2; ch++) {
        ax[ch] = *(const short8*)(x_bf + (size_t)nclamp * H + ch * 32 + g * 8);
        ah[ch] = *(const short8*)(h_bf + (size_t)nclamp * H + ch * 32 + g * 8);
    }

    f32x4 gi[12], gh[12];
#pragma unroll
    for (int jb = 0; jb < 12; jb++) {
        gi[jb] = (f32x4){0.f, 0.f, 0.f, 0.f};
        gh[jb] = (f32x4){0.f, 0.f, 0.f, 0.f};
    }

#pragma unroll
    for (int jb = 0; jb < 12; jb++) {
        const unsigned short* wi = wih_bf + (size_t)(jb * 16 + c) * H + g * 8;
        const unsigned short* wh = whh_bf + (size_t)(jb * 16 + c) * H + g * 8;
        short8 wi0 = *(const short8*)(wi);
        short8 wi1 = *(const short8*)(wi + 32);
        short8 wh0 = *(const short8*)(wh);
        short8 wh1 = *(const short8*)(wh + 32);
        gi[jb] = __builtin_amdgcn_mfma_f32_16x16x32_bf16(ax[0], wi0, gi[jb], 0, 0, 0);
        gi[jb] = __builtin_amdgcn_mfma_f32_16x16x32_bf16(ax[1], wi1, gi[jb], 0, 0, 0);
        gh[jb] = __builtin_amdgcn_mfma_f32_16x16x32_bf16(ah[0], wh0, gh[jb], 0, 0, 0);
        gh[jb] = __builtin_amdgcn_mfma_f32_16x16x32_bf16(ah[1], wh1, gh[jb], 0, 0, 0);
    }

    float pa[4] = {0.f, 0.f, 0.f, 0.f};
    float pb[4] = {0.f, 0.f, 0.f, 0.f};
#pragma unroll
    for (int jb = 0; jb < 4; jb++) {
        int j = jb * 16 + c;
        float br = bih[j] + bhh[j];
        float bz = bih[H + j] + bhh[H + j];
        float bin_ = bih[2 * H + j];
        float bhn_ = bhh[2 * H + j];
        float wga = Wg[j], wgb = Wg[H + j];
#pragma unroll
        for (int q = 0; q < 4; q++) {
            int node = nbase + g * 4 + q;
            float r = sigmoidf_(gi[jb][q] + gh[jb][q] + br);
            float z = sigmoidf_(gi[jb + 4][q] + gh[jb + 4][q] + bz);
            float nn = tanhf_(gi[jb + 8][q] + bin_ + r * (gh[jb + 8][q] + bhn_));
            size_t idx = (size_t)node * H + j;
            float hp = bf2f(h_bf[idx]);
            float ho = (1.0f - z) * nn + z * hp;
            h_bf[idx] = f2bf(ho);
            pa[q] += ho * wga;
            pb[q] += ho * wgb;
        }
    }
#pragma unroll
    for (int m = 1; m < 16; m <<= 1) {
#pragma unroll
        for (int q = 0; q < 4; q++) {
            pa[q] += __shfl_xor(pa[q], m);
            pb[q] += __shfl_xor(pb[q], m);
        }
    }
    if (c == 0) {
#pragma unroll
        for (int q = 0; q < 4; q++) {
            int node = nbase + g * 4 + q;
            a_gate[node] = pa[q];
            b_gate[node] = pb[q];
        }
    }
}

// ---------------------------------------------------------------------------
// Final predictor: out[e] = pa[src] + pb[dst] + b_pred  (4 edges/thread)
__global__ __launch_bounds__(256) void predict_kernel(
    const int* __restrict__ src, const int* __restrict__ dst,
    const float* __restrict__ pa, const float* __restrict__ pb,
    const float* __restrict__ b_pred, float* __restrict__ out, int E)
{
    int e4 = (blockIdx.x * 256 + threadIdx.x) * 4;
    float bp = b_pred[0];
    if (e4 + 3 < E) {
        int4 s = *(const int4*)(src + e4);
        int4 d = *(const int4*)(dst + e4);
        float4 o;
        o.x = pa[s.x] + pb[d.x] + bp;
        o.y = pa[s.y] + pb[d.y] + bp;
        o.z = pa[s.z] + pb[d.z] + bp;
        o.w = pa[s.w] + pb[d.w] + bp;
        *(float4*)(out + e4) = o;
    } else {
        for (int e = e4; e < E; e++)
            out[e] = pa[src[e]] + pb[dst[e]] + bp;
    }
}

// ---------------------------------------------------------------------------
extern "C" void kernel_launch(void* const* d_in, const int* in_sizes, int n_in,
                              void* d_out, int out_size, void* d_ws, size_t ws_size,
                              hipStream_t stream) {
    const float* features = (const float*)d_in[0];
    const int*   src      = (const int*)d_in[1];
    const int*   dst      = (const int*)d_in[2];
    const float* W_in     = (const float*)d_in[3];
    const float* b_in     = (const float*)d_in[4];
    const float* W_edge   = (const float*)d_in[5];
    const float* b_edge   = (const float*)d_in[6];
    const float* Wih      = (const float*)d_in[7];
    const float* Whh      = (const float*)d_in[8];
    const float* bih      = (const float*)d_in[9];
    const float* bhh      = (const float*)d_in[10];
    const float* W_pred   = (const float*)d_in[11];
    const float* b_pred   = (const float*)d_in[12];
    float* out = (float*)d_out;

    int N = in_sizes[0] / 16;
    int E = in_sizes[1];
    int L = in_sizes[7] / (H3 * H);
    int per = L * H3 * H;

    int nb_nodes = (N + 255) / 256;
    int nb_agg   = (N + 3) / 4;
    int nb_gru   = (N + 63) / 64;
    int nb_conv  = (2 * per + 255) / 256;
    int nb_pred  = (E + 1023) / 1024;

    int nb_c = (E + 4095) / 4096;     // bucket hist/scatter blocks (4096 edges)
    int NB   = (N + 255) / 256;       // number of buckets
    int M    = 256 * nb_c;
    int mb   = (M + 255) / 256;
    int nb_s3 = (M + 1 + 255) / 256;

    // workspace layout
    unsigned short* h_bf = (unsigned short*)d_ws;                     // N*64 bf16
    unsigned short* hnew_bf = h_bf + (size_t)N * H;                   // N*64 bf16
    unsigned short* w_bf = hnew_bf + (size_t)N * H;                   // 2*per bf16
    float* a_gate = (float*)(w_bf + 2 * per);                         // N
    float* b_gate = a_gate + N;                                       // N
    int* offsets  = (int*)(b_gate + N);                               // N+1
    unsigned* pk  = (unsigned*)(offsets + N + 1);                     // E
    unsigned short* csr16 = (unsigned short*)(pk + E);                // E (even)
    int* bhist = (int*)(csr16 + E);                                   // M
    int* bloc  = bhist + M;                                           // M
    int* sbh   = bloc + M;                                            // M+1
    int* bsum  = sbh + M + 1;                                         // mb

    // fused setup: input linear | weight convert | bucket hist
    setup_kernel<<<nb_nodes + nb_conv + nb_c, 256, 0, stream>>>(
        features, W_in, b_in, W_edge, h_bf, a_gate, b_gate,
        Wih, Whh, w_bf, dst, bhist,
        N, E, per, nb_nodes, nb_conv, nb_c);

    // CSR build (bucket sort)
    scan_pass1<<<mb, 256, 0, stream>>>(bhist, bloc, bsum, M);
    scan_pass3c<<<nb_s3, 256, 0, stream>>>(bloc, bsum, sbh, M, E, mb);
    bucket_scatter_kernel<<<nb_c, 1024, 0, stream>>>(src, dst, sbh, pk, E, nb_c);
    bucket_finalize_kernel<<<NB, 1024, 0, stream>>>(pk, sbh, offsets, csr16, N, E, nb_c, NB);

    for (int l = 0; l < L; l++) {
        aggregate_kernel<<<nb_agg, 256, 0, stream>>>(
            h_bf, a_gate, b_gate, offsets, csr16, b_edge, hnew_bf, N);
        const float* Wg = (l < L - 1) ? W_edge : W_pred;
        gru_mfma_kernel<<<nb_gru, 256, 0, stream>>>(
            hnew_bf, h_bf,
            w_bf + (size_t)l * H3 * H,
            w_bf + (size_t)per + (size_t)l * H3 * H,
            bih + (size_t)l * H3, bhh + (size_t)l * H3,
            Wg, a_gate, b_gate, N);
    }

    predict_kernel<<<nb_pred, 256, 0, stream>>>(src, dst, a_gate, b_gate, b_pred, out, E);
}